// Round 2
// baseline (556.418 us; speedup 1.0000x reference)
//
#include <hip/hip_runtime.h>

// Problem constants
#define BATCH 2048
#define KIN   64
#define KOUT  64
#define NPT   256                        // block FFT length
#define NF    129                        // half-spectrum bins
#define FSTRIDE (BATCH * KIN)            // 131072 complex elements per f-plane row
#define XPLANE ((size_t)NF * FSTRIDE)    // re/im floats per plane (offset bookkeeping)
#define WPLANE (NF * KIN * KOUT)         // 528,384 floats
#define NFP 133                          // padded staging row stride (gcd(5,32)=1)

// wave-level LDS fence: wave64 lockstep + in-order DS pipe makes this a valid
// substitute for __syncthreads() on wave-private LDS regions.
#define WAVE_SYNC() __asm__ volatile("s_waitcnt lgkmcnt(0)" ::: "memory")

// ---------------------------------------------------------------------------
// XOR bank swizzle for the 256-entry float2 FFT buffer (no pad needed).
// Base-4 digits of i = (d3 d2 d1 d0); slot = i with d1^=d3, d0^=d2.
// All four in-place radix-4 stage patterns + digit-reversed unpack reads land
// <=2 lanes/bank (free). Bijective involution on 0..255.
// ---------------------------------------------------------------------------
__device__ __forceinline__ int SWZ(int i) {
  return i ^ (((i >> 6) & 3) << 2) ^ ((i >> 4) & 3);
}
// 4-digit base-4 reversal (in-place DIF leaves X[p] at slot REV4(p);
// in-place DIT wants Z[f] written at slot REV4(f)).
__device__ __forceinline__ int REV4(int f) {
  return ((f & 3) << 6) | ((f & 12) << 2) | ((f >> 2) & 12) | ((f >> 6) & 3);
}
__device__ __forceinline__ float2 cmul(float2 v, float c, float s) {
  return make_float2(v.x * c - v.y * s, v.y * c + v.x * s);
}

struct TW { float c1, s1, c2, s2, c3, s3; };
__device__ __forceinline__ TW mk_tw(int unit, float C) {
  TW t; float s, c;
  __sincosf(C * (float)unit, &s, &c);
  t.c1 = c; t.s1 = s;
  t.c2 = c * c - s * s;  t.s2 = 2.f * c * s;
  t.c3 = t.c2 * c - t.s2 * s;  t.s3 = t.c2 * s + t.s2 * c;
  return t;
}

struct Quad { int i0, i1, i2, i3; };
__device__ __forceinline__ Quad mkquad(int base, int M) {
  Quad q;
  q.i0 = SWZ(base); q.i1 = SWZ(base + M);
  q.i2 = SWZ(base + 2 * M); q.i3 = SWZ(base + 3 * M);
  return q;
}

// Forward (sign -1) in-place DIF radix-4 stage: butterfly, then twiddle.
// b0=t0+t2; b1=t1-i*t3; b2=t0-t2; b3=t1+i*t3;  out_k = b_k * W_{4M}^{k q}.
template<bool TWID>
__device__ __forceinline__ void dif_stage(float2* A, const Quad& q, const TW& w) {
  float2 a0 = A[q.i0], a1 = A[q.i1], a2 = A[q.i2], a3 = A[q.i3];
  float t0x = a0.x + a2.x, t0y = a0.y + a2.y;
  float t1x = a0.x - a2.x, t1y = a0.y - a2.y;
  float t2x = a1.x + a3.x, t2y = a1.y + a3.y;
  float t3x = a1.x - a3.x, t3y = a1.y - a3.y;
  float2 b0 = make_float2(t0x + t2x, t0y + t2y);
  float2 b2 = make_float2(t0x - t2x, t0y - t2y);
  float2 b1 = make_float2(t1x + t3y, t1y - t3x);   // t1 - i*t3
  float2 b3 = make_float2(t1x - t3y, t1y + t3x);   // t1 + i*t3
  A[q.i0] = b0;
  A[q.i1] = TWID ? cmul(b1, w.c1, w.s1) : b1;
  A[q.i2] = TWID ? cmul(b2, w.c2, w.s2) : b2;
  A[q.i3] = TWID ? cmul(b3, w.c3, w.s3) : b3;
  WAVE_SYNC();
}

// Inverse (sign +1) in-place DIT radix-4 stage: twiddle first, then butterfly.
// out0=A+C; out1=B+iD; out2=A-C; out3=B-iD.
template<bool TWID>
__device__ __forceinline__ void dit_stage(float2* A, const Quad& q, const TW& w) {
  float2 a0 = A[q.i0], a1 = A[q.i1], a2 = A[q.i2], a3 = A[q.i3];
  if (TWID) {
    a1 = cmul(a1, w.c1, w.s1);
    a2 = cmul(a2, w.c2, w.s2);
    a3 = cmul(a3, w.c3, w.s3);
  }
  float Ax = a0.x + a2.x, Ay = a0.y + a2.y;
  float Bx = a0.x - a2.x, By = a0.y - a2.y;
  float Cx = a1.x + a3.x, Cy = a1.y + a3.y;
  float Dx = a1.x - a3.x, Dy = a1.y - a3.y;
  A[q.i0] = make_float2(Ax + Cx, Ay + Cy);
  A[q.i2] = make_float2(Ax - Cx, Ay - Cy);
  A[q.i1] = make_float2(Bx - Dy, By + Dx);   // B + iD
  A[q.i3] = make_float2(Bx + Dy, By - Dx);   // B - iD
  WAVE_SYNC();
}

// ---------------------------------------------------------------------------
// k0: tiled transpose W[i][j][f] -> Wtr/Wti[f][j*64+i], both sides coalesced.
// ---------------------------------------------------------------------------
__global__ __launch_bounds__(256) void k0_wtrans(const float* __restrict__ Wre,
                                                 const float* __restrict__ Wim,
                                                 float* __restrict__ Wtr,
                                                 float* __restrict__ Wti) {
  __shared__ float T[32][33];
  const int f0 = blockIdx.y * 32;       // 0,32,64,96,128
  const int d0 = blockIdx.x * 32;       // dest inner index d = j*64+i
  const int t  = threadIdx.x;
  const int a  = t & 31, g = t >> 5;
#pragma unroll
  for (int pl = 0; pl < 2; ++pl) {
    const float* src = pl ? Wim : Wre;
    float* dst = pl ? Wti : Wtr;
    if (pl) __syncthreads();
#pragma unroll
    for (int it = 0; it < 4; ++it) {
      int dl = g + it * 8;
      int d  = d0 + dl;
      int s  = (d & 63) * 64 + (d >> 6);   // source row i*64+j
      int f  = f0 + a;
      if (f < NF) T[dl][a] = src[(size_t)s * NF + f];
    }
    __syncthreads();
#pragma unroll
    for (int it = 0; it < 4; ++it) {
      int fl = g + it * 8;
      int f  = f0 + fl;
      if (f < NF) dst[(size_t)f * (KIN * KOUT) + d0 + a] = T[a][fl];
    }
  }
}

// ---------------------------------------------------------------------------
// k1: packed rfft (2 real blocks per complex FFT), in-place DIF radix-4 in a
// wave-private swizzled LDS buffer (digit-reversed output absorbed into the
// unpack read indices). 16-row staging (2 phases) -> 24.9 KB LDS -> ~6 blk/CU.
// Global loads software-pipelined ahead of the sync cluster. Output plane is
// interleaved complex: Xc[f][b*64+j] as float2.
// ---------------------------------------------------------------------------
__global__ __launch_bounds__(256) void k1_rfft(const float* __restrict__ x,
                                               float2* __restrict__ Xc) {
  __shared__ float2 fbuf[4][256];       // 8.2 KB, swizzled, in-place
  __shared__ float Sr[16 * NFP];        // 8.5 KB
  __shared__ float Si[16 * NFP];        // 8.5 KB
  const int wave = threadIdx.x >> 6, lane = threadIdx.x & 63;
  const int b = blockIdx.x >> 1, h = blockIdx.x & 1;
  float2* A = fbuf[wave];

  // precomputed slot quads per stage (read set == write set, lane-private)
  const Quad q0 = mkquad(lane, 64);
  const Quad q1 = mkquad(((lane >> 4) << 6) + (lane & 15), 16);
  const Quad q2 = mkquad(((lane >> 2) << 4) + (lane & 3), 4);
  const Quad q3 = mkquad(lane << 2, 1);          // also the pack slots 4l+k
  const float C = -6.28318530717958647692f / 256.f;
  const TW tw0 = mk_tw(lane, C);
  const TW tw1 = mk_tw(4 * (lane & 15), C);
  const TW tw2 = mk_tw(16 * (lane & 3), C);
  // digit-reversed unpack slots
  const int uf  = SWZ(REV4(lane));
  const int ug  = SWZ(REV4(lane + 64));
  const int ufm = SWZ(REV4((256 - lane) & 255));
  const int ugm = SWZ(REV4(192 - lane));

  const size_t rowbase = (size_t)b * 64 + h * 32;
  float4 va = reinterpret_cast<const float4*>(x + (rowbase + 2 * wave) * NPT)[lane];
  float4 vb = reinterpret_cast<const float4*>(x + (rowbase + 2 * wave + 1) * NPT)[lane];

#pragma unroll
  for (int half = 0; half < 2; ++half) {
    if (half) __syncthreads();          // write-out reads of prev half done
#pragma unroll
    for (int uu = 0; uu < 2; ++uu) {
      const int u = half * 2 + uu;
      const int p = u * 4 + wave;                  // packed-FFT index 0..15
      float4 na = va, nb = vb;
      if (u < 3) {                                 // prefetch next iteration
        const size_t nidx = rowbase + 2 * ((u + 1) * 4 + wave);
        na = reinterpret_cast<const float4*>(x + nidx * NPT)[lane];
        nb = reinterpret_cast<const float4*>(x + (nidx + 1) * NPT)[lane];
      }
      A[q3.i0] = make_float2(va.x, vb.x);
      A[q3.i1] = make_float2(va.y, vb.y);
      A[q3.i2] = make_float2(va.z, vb.z);
      A[q3.i3] = make_float2(va.w, vb.w);
      WAVE_SYNC();
      dif_stage<true >(A, q0, tw0);
      dif_stage<true >(A, q1, tw1);
      dif_stage<true >(A, q2, tw2);
      dif_stage<false>(A, q3, tw0);
      // unpack: X1(f)=0.5(Z(f)+conj(Z(-f))), X2(f)=-0.5i(Z(f)-conj(Z(-f)))
      float2 zf  = A[uf];
      float2 zg  = A[ug];
      float2 zfm = A[ufm];
      float2 zgm = A[ugm];
      const int r1 = (2 * p - half * 16) * NFP;    // staging row offsets
      const int r2 = r1 + NFP;
      Sr[r1 + lane]      = 0.5f * (zf.x + zfm.x);
      Si[r1 + lane]      = 0.5f * (zf.y - zfm.y);
      Sr[r2 + lane]      = 0.5f * (zf.y + zfm.y);
      Si[r2 + lane]      = 0.5f * (zfm.x - zf.x);
      Sr[r1 + lane + 64] = 0.5f * (zg.x + zgm.x);
      Si[r1 + lane + 64] = 0.5f * (zg.y - zgm.y);
      Sr[r2 + lane + 64] = 0.5f * (zg.y + zgm.y);
      Si[r2 + lane + 64] = 0.5f * (zgm.x - zg.x);
      if (lane == 0) {
        float2 zn = A[SWZ(REV4(128))];             // Nyquist: both spectra real
        Sr[r1 + 128] = zn.x;  Si[r1 + 128] = 0.f;
        Sr[r2 + 128] = zn.y;  Si[r2 + 128] = 0.f;
      }
      WAVE_SYNC();
      va = na; vb = nb;
    }
    __syncthreads();
    // coalesced interleaved write-out: 16 consecutive idx per f, float2 each
    const int c = threadIdx.x & 15, fg = threadIdx.x >> 4;
    const size_t baseidx = rowbase + half * 16 + c;
#pragma unroll
    for (int it = 0; it < 9; ++it) {
      int f = fg + it * 16;
      if (f < NF)
        Xc[(size_t)f * FSTRIDE + baseidx] =
            make_float2(Sr[c * NFP + f], Si[c * NFP + f]);
    }
  }
}

// ---------------------------------------------------------------------------
// k2: per-frequency complex GEMM  O[b][i] = sum_j X[b][j] * conj(W[i][j])
// Interleaved-complex f-major plane; X LDS tile un-padded with XOR swizzle on
// the r-block (transposed scalar stores drop from 16-way to 2-way conflicts;
// b128 inner-loop reads stay conflict-free). In-place over Xc.
// ---------------------------------------------------------------------------
__device__ __forceinline__ int XIDX(int j, int r) {
  int rc = r >> 2;
  int rcs = (rc & 8) | ((rc ^ (j >> 1)) & 7);
  return (j << 6) + (rcs << 2) + (r & 3);
}

__global__ __launch_bounds__(256) void k2_cgemm(float2* __restrict__ Xc,
                                                const float* __restrict__ Wtr,
                                                const float* __restrict__ Wti) {
  __shared__ __align__(16) float Xlr[64 * 64];
  __shared__ __align__(16) float Xli[64 * 64];
  __shared__ __align__(16) float Wlr[64 * 68];
  __shared__ __align__(16) float Wli[64 * 68];

  const int f  = blockIdx.y;
  const int b0 = blockIdx.x * 64;
  const int t  = threadIdx.x;
  const size_t xbase = (size_t)f * FSTRIDE + (size_t)b0 * 64;  // complex units
  const float* wpr = Wtr + (size_t)f * (KIN * KOUT);
  const float* wpi = Wti + (size_t)f * (KIN * KOUT);

  // W tile: [j][i], vector load + vector store (already in [j][i] layout)
#pragma unroll
  for (int it = 0; it < 4; ++it) {
    int n4 = (it * 256 + t) * 4;
    int j = n4 >> 6, i0 = n4 & 63;
    float4 wr = *reinterpret_cast<const float4*>(wpr + n4);
    float4 wi = *reinterpret_cast<const float4*>(wpi + n4);
    *reinterpret_cast<float4*>(&Wlr[j * 68 + i0]) = wr;
    *reinterpret_cast<float4*>(&Wli[j * 68 + i0]) = wi;
  }
  // X tile: float4 = 2 complex; transposed swizzled scalar stores -> [j][r]
#pragma unroll
  for (int it = 0; it < 8; ++it) {
    int n2 = (it * 256 + t) * 2;
    int j0 = n2 & 63, r = n2 >> 6;
    float4 v = *reinterpret_cast<const float4*>(
                   reinterpret_cast<const float*>(Xc + xbase) + 2 * n2);
    Xlr[XIDX(j0, r)] = v.x;      Xli[XIDX(j0, r)] = v.y;
    Xlr[XIDX(j0 + 1, r)] = v.z;  Xli[XIDX(j0 + 1, r)] = v.w;
  }
  __syncthreads();

  const int tx = t & 15, ty = t >> 4;
  const int i0 = tx * 4, r0 = ty * 4;
  float aR[4][4] = {};
  float aI[4][4] = {};

#pragma unroll 4
  for (int j = 0; j < 64; ++j) {
    float4 xr = *reinterpret_cast<const float4*>(&Xlr[XIDX(j, r0)]);
    float4 xi = *reinterpret_cast<const float4*>(&Xli[XIDX(j, r0)]);
    float4 wr = *reinterpret_cast<const float4*>(&Wlr[j * 68 + i0]);
    float4 wi = *reinterpret_cast<const float4*>(&Wli[j * 68 + i0]);
    float xra[4] = {xr.x, xr.y, xr.z, xr.w};
    float xia[4] = {xi.x, xi.y, xi.z, xi.w};
    float wra[4] = {wr.x, wr.y, wr.z, wr.w};
    float wia[4] = {wi.x, wi.y, wi.z, wi.w};
#pragma unroll
    for (int a = 0; a < 4; ++a)
#pragma unroll
      for (int c = 0; c < 4; ++c) {
        // X * conj(W): re += xr*wr + xi*wi ; im += xi*wr - xr*wi
        aR[a][c] += xra[a] * wra[c] + xia[a] * wia[c];
        aI[a][c] += xia[a] * wra[c] - xra[a] * wia[c];
      }
  }

#pragma unroll
  for (int a = 0; a < 4; ++a) {
    float* gp = reinterpret_cast<float*>(Xc + xbase + (size_t)(r0 + a) * 64 + i0);
    *reinterpret_cast<float4*>(gp) =
        make_float4(aR[a][0], aI[a][0], aR[a][1], aI[a][1]);
    *reinterpret_cast<float4*>(gp + 4) =
        make_float4(aR[a][2], aI[a][2], aR[a][3], aI[a][3]);
  }
}

// ---------------------------------------------------------------------------
// k3: coalesced interleaved gather (prefetched), conjugate-symmetric spectrum
// written at digit-reversed slots, in-place DIT radix-4 inverse FFT (natural-
// order output), packed: one complex iFFT -> two real output blocks.
// ---------------------------------------------------------------------------
__global__ __launch_bounds__(256) void k3_irfft(const float2* __restrict__ Oc,
                                                float* __restrict__ out) {
  __shared__ float2 fbuf[4][256];
  __shared__ float Sr[16 * NFP];
  __shared__ float Si[16 * NFP];
  const int wave = threadIdx.x >> 6, lane = threadIdx.x & 63;
  const int b = blockIdx.x >> 1, h = blockIdx.x & 1;
  float2* A = fbuf[wave];
  const int c = threadIdx.x & 15, fg = threadIdx.x >> 4;
  const size_t rowbase = (size_t)b * 64 + h * 32;

  const Quad q0 = mkquad(lane, 64);
  const Quad q1 = mkquad(((lane >> 4) << 6) + (lane & 15), 16);
  const Quad q2 = mkquad(((lane >> 2) << 4) + (lane & 3), 4);
  const Quad q3 = mkquad(lane << 2, 1);
  const float C = 6.28318530717958647692f / 256.f;
  const TW tw0 = mk_tw(lane, C);
  const TW tw1 = mk_tw(4 * (lane & 15), C);
  const TW tw2 = mk_tw(16 * (lane & 3), C);
  const int wf  = SWZ(REV4(lane));
  const int wg  = SWZ(REV4(lane + 64));
  const int wfm = SWZ(REV4((256 - lane) & 255));  // lane>=1 only
  const int wgm = SWZ(REV4(192 - lane));

  // prefetch half-0 gathers
  float2 gv[9], nv[9];
#pragma unroll
  for (int it = 0; it < 9; ++it) {
    int f = fg + it * 16;
    gv[it] = (f < NF) ? Oc[(size_t)f * FSTRIDE + rowbase + c]
                      : make_float2(0.f, 0.f);
  }
#pragma unroll
  for (int half = 0; half < 2; ++half) {
    if (half == 0) {
      // issue half-1 gathers now; latency hides under half-0 FFT phase
#pragma unroll
      for (int it = 0; it < 9; ++it) {
        int f = fg + it * 16;
        nv[it] = (f < NF) ? Oc[(size_t)f * FSTRIDE + rowbase + 16 + c]
                          : make_float2(0.f, 0.f);
      }
    }
    if (half) __syncthreads();          // FFT reads of prev half done
#pragma unroll
    for (int it = 0; it < 9; ++it) {
      int f = fg + it * 16;
      if (f < NF) { Sr[c * NFP + f] = gv[it].x; Si[c * NFP + f] = gv[it].y; }
    }
    __syncthreads();
#pragma unroll
    for (int uu = 0; uu < 2; ++uu) {
      const int u = half * 2 + uu;
      const int p = u * 4 + wave;
      const int r1 = (2 * p - half * 16) * NFP, r2 = r1 + NFP;
      float a1r = Sr[r1 + lane],      a1i = Si[r1 + lane];
      float b1r = Sr[r1 + lane + 64], b1i = Si[r1 + lane + 64];
      float a2r = Sr[r2 + lane],      a2i = Si[r2 + lane];
      float b2r = Sr[r2 + lane + 64], b2i = Si[r2 + lane + 64];
      // Z(f) = O1(f) + i*O2(f);  Z(256-f) = conj(O1(f)) + i*conj(O2(f))
      A[wf]  = make_float2(a1r - a2i, a1i + a2r);            // f = 0..63
      A[wg]  = make_float2(b1r - b2i, b1i + b2r);            // f = 64..127
      if (lane) A[wfm] = make_float2(a1r + a2i, a2r - a1i);  // f = 193..255
      A[wgm] = make_float2(b1r + b2i, b2r - b1i);            // f = 129..192
      if (lane == 0) {
        float n1r = Sr[r1 + 128], n1i = Si[r1 + 128];
        float n2r = Sr[r2 + 128], n2i = Si[r2 + 128];
        A[SWZ(REV4(128))] = make_float2(n1r - n2i, n1i + n2r);
      }
      WAVE_SYNC();
      dit_stage<false>(A, q3, tw0);
      dit_stage<true >(A, q2, tw2);
      dit_stage<true >(A, q1, tw1);
      dit_stage<true >(A, q0, tw0);
      const float s = 1.0f / 256.f;
      float2 e0 = A[q3.i0], e1 = A[q3.i1], e2 = A[q3.i2], e3 = A[q3.i3];
      float4 o1 = make_float4(e0.x * s, e1.x * s, e2.x * s, e3.x * s);
      float4 o2 = make_float4(e0.y * s, e1.y * s, e2.y * s, e3.y * s);
      const size_t idx1 = rowbase + 2 * p;
      reinterpret_cast<float4*>(out + idx1 * NPT)[lane] = o1;
      reinterpret_cast<float4*>(out + (idx1 + 1) * NPT)[lane] = o2;
      WAVE_SYNC();                      // output reads done before next build
    }
#pragma unroll
    for (int it = 0; it < 9; ++it) gv[it] = nv[it];
  }
}

// ---------------------------------------------------------------------------
extern "C" void kernel_launch(void* const* d_in, const int* in_sizes, int n_in,
                              void* d_out, int out_size, void* d_ws, size_t ws_size,
                              hipStream_t stream) {
  const float* x   = (const float*)d_in[0];
  const float* Wre = (const float*)d_in[1];
  const float* Wim = (const float*)d_in[2];
  float* out = (float*)d_out;
  float* ws  = (float*)d_ws;

  float2* Xc = reinterpret_cast<float2*>(ws);  // interleaved plane [f][b*64+j]
  float* Wtr = ws + 2 * XPLANE;                // [f][j*64+i]
  float* Wti = Wtr + WPLANE;
  // ws use: (2*XPLANE + 2*WPLANE)*4 B ~= 139.5 MB (same footprint as before)

  hipLaunchKernelGGL(k0_wtrans, dim3(128, 5), dim3(256), 0, stream,
                     Wre, Wim, Wtr, Wti);
  hipLaunchKernelGGL(k1_rfft, dim3(BATCH * 2), dim3(256), 0, stream,
                     x, Xc);
  hipLaunchKernelGGL(k2_cgemm, dim3(BATCH / 64, NF), dim3(256), 0, stream,
                     Xc, Wtr, Wti);
  hipLaunchKernelGGL(k3_irfft, dim3(BATCH * 2), dim3(256), 0, stream,
                     Xc, out);
}

// Round 3
// 468.132 us; speedup vs baseline: 1.1886x; 1.1886x over previous
//
#include <hip/hip_runtime.h>

// Problem constants
#define BATCH 2048
#define KIN   64
#define KOUT  64
#define NPT   256                        // block FFT length
#define NF    129                        // half-spectrum bins
#define FSTRIDE (BATCH * KIN)            // 131072 complex elements per f-plane row
#define XPLANE ((size_t)NF * FSTRIDE)    // re/im floats per plane (offset bookkeeping)
#define WPLANE (NF * KIN * KOUT)         // 528,384 floats
#define NFP 133                          // padded staging row stride (gcd(5,32)=1)

// wave-level LDS fence: wave64 lockstep + in-order DS pipe makes this a valid
// substitute for __syncthreads() on wave-private LDS regions.
#define WAVE_SYNC() __asm__ volatile("s_waitcnt lgkmcnt(0)" ::: "memory")

// ---------------------------------------------------------------------------
// XOR bank swizzle for the 256-entry float2 FFT buffer (no pad needed).
// Base-4 digits of i = (d3 d2 d1 d0); slot = i with d1^=d3, d0^=d2.
// All four in-place radix-4 stage patterns + digit-reversed unpack reads land
// <=2 lanes/bank (free). Bijective involution on 0..255.
// NOTE: used ONLY inside the FFT kernels (k1/k3) where slot indices are
// precomputed once per thread — never in a hot GEMM loop (round-2 lesson).
// ---------------------------------------------------------------------------
__device__ __forceinline__ int SWZ(int i) {
  return i ^ (((i >> 6) & 3) << 2) ^ ((i >> 4) & 3);
}
// 4-digit base-4 reversal (in-place DIF leaves X[p] at slot REV4(p);
// in-place DIT wants Z[f] written at slot REV4(f)).
__device__ __forceinline__ int REV4(int f) {
  return ((f & 3) << 6) | ((f & 12) << 2) | ((f >> 2) & 12) | ((f >> 6) & 3);
}
__device__ __forceinline__ float2 cmul(float2 v, float c, float s) {
  return make_float2(v.x * c - v.y * s, v.y * c + v.x * s);
}

struct TW { float c1, s1, c2, s2, c3, s3; };
__device__ __forceinline__ TW mk_tw(int unit, float C) {
  TW t; float s, c;
  __sincosf(C * (float)unit, &s, &c);
  t.c1 = c; t.s1 = s;
  t.c2 = c * c - s * s;  t.s2 = 2.f * c * s;
  t.c3 = t.c2 * c - t.s2 * s;  t.s3 = t.c2 * s + t.s2 * c;
  return t;
}

struct Quad { int i0, i1, i2, i3; };
__device__ __forceinline__ Quad mkquad(int base, int M) {
  Quad q;
  q.i0 = SWZ(base); q.i1 = SWZ(base + M);
  q.i2 = SWZ(base + 2 * M); q.i3 = SWZ(base + 3 * M);
  return q;
}

// Forward (sign -1) in-place DIF radix-4 stage: butterfly, then twiddle.
template<bool TWID>
__device__ __forceinline__ void dif_stage(float2* A, const Quad& q, const TW& w) {
  float2 a0 = A[q.i0], a1 = A[q.i1], a2 = A[q.i2], a3 = A[q.i3];
  float t0x = a0.x + a2.x, t0y = a0.y + a2.y;
  float t1x = a0.x - a2.x, t1y = a0.y - a2.y;
  float t2x = a1.x + a3.x, t2y = a1.y + a3.y;
  float t3x = a1.x - a3.x, t3y = a1.y - a3.y;
  float2 b0 = make_float2(t0x + t2x, t0y + t2y);
  float2 b2 = make_float2(t0x - t2x, t0y - t2y);
  float2 b1 = make_float2(t1x + t3y, t1y - t3x);   // t1 - i*t3
  float2 b3 = make_float2(t1x - t3y, t1y + t3x);   // t1 + i*t3
  A[q.i0] = b0;
  A[q.i1] = TWID ? cmul(b1, w.c1, w.s1) : b1;
  A[q.i2] = TWID ? cmul(b2, w.c2, w.s2) : b2;
  A[q.i3] = TWID ? cmul(b3, w.c3, w.s3) : b3;
  WAVE_SYNC();
}

// Inverse (sign +1) in-place DIT radix-4 stage: twiddle first, then butterfly.
template<bool TWID>
__device__ __forceinline__ void dit_stage(float2* A, const Quad& q, const TW& w) {
  float2 a0 = A[q.i0], a1 = A[q.i1], a2 = A[q.i2], a3 = A[q.i3];
  if (TWID) {
    a1 = cmul(a1, w.c1, w.s1);
    a2 = cmul(a2, w.c2, w.s2);
    a3 = cmul(a3, w.c3, w.s3);
  }
  float Ax = a0.x + a2.x, Ay = a0.y + a2.y;
  float Bx = a0.x - a2.x, By = a0.y - a2.y;
  float Cx = a1.x + a3.x, Cy = a1.y + a3.y;
  float Dx = a1.x - a3.x, Dy = a1.y - a3.y;
  A[q.i0] = make_float2(Ax + Cx, Ay + Cy);
  A[q.i2] = make_float2(Ax - Cx, Ay - Cy);
  A[q.i1] = make_float2(Bx - Dy, By + Dx);   // B + iD
  A[q.i3] = make_float2(Bx + Dy, By - Dx);   // B - iD
  WAVE_SYNC();
}

// ---------------------------------------------------------------------------
// k0: tiled transpose W[i][j][f] -> Wtr/Wti[f][j*64+i], both sides coalesced.
// ---------------------------------------------------------------------------
__global__ __launch_bounds__(256) void k0_wtrans(const float* __restrict__ Wre,
                                                 const float* __restrict__ Wim,
                                                 float* __restrict__ Wtr,
                                                 float* __restrict__ Wti) {
  __shared__ float T[32][33];
  const int f0 = blockIdx.y * 32;       // 0,32,64,96,128
  const int d0 = blockIdx.x * 32;       // dest inner index d = j*64+i
  const int t  = threadIdx.x;
  const int a  = t & 31, g = t >> 5;
#pragma unroll
  for (int pl = 0; pl < 2; ++pl) {
    const float* src = pl ? Wim : Wre;
    float* dst = pl ? Wti : Wtr;
    if (pl) __syncthreads();
#pragma unroll
    for (int it = 0; it < 4; ++it) {
      int dl = g + it * 8;
      int d  = d0 + dl;
      int s  = (d & 63) * 64 + (d >> 6);   // source row i*64+j
      int f  = f0 + a;
      if (f < NF) T[dl][a] = src[(size_t)s * NF + f];
    }
    __syncthreads();
#pragma unroll
    for (int it = 0; it < 4; ++it) {
      int fl = g + it * 8;
      int f  = f0 + fl;
      if (f < NF) dst[(size_t)f * (KIN * KOUT) + d0 + a] = T[a][fl];
    }
  }
}

// ---------------------------------------------------------------------------
// k1: packed rfft (2 real blocks per complex FFT), in-place DIF radix-4 in a
// wave-private swizzled LDS buffer (digit-reversed output absorbed into the
// unpack read indices). 16-row staging (2 phases) -> ~25 KB LDS.
// Global loads software-pipelined. Output plane interleaved complex.
// ---------------------------------------------------------------------------
__global__ __launch_bounds__(256) void k1_rfft(const float* __restrict__ x,
                                               float2* __restrict__ Xc) {
  __shared__ float2 fbuf[4][256];       // 8.2 KB, swizzled, in-place
  __shared__ float Sr[16 * NFP];        // 8.5 KB
  __shared__ float Si[16 * NFP];        // 8.5 KB
  const int wave = threadIdx.x >> 6, lane = threadIdx.x & 63;
  const int b = blockIdx.x >> 1, h = blockIdx.x & 1;
  float2* A = fbuf[wave];

  const Quad q0 = mkquad(lane, 64);
  const Quad q1 = mkquad(((lane >> 4) << 6) + (lane & 15), 16);
  const Quad q2 = mkquad(((lane >> 2) << 4) + (lane & 3), 4);
  const Quad q3 = mkquad(lane << 2, 1);          // also the pack slots 4l+k
  const float C = -6.28318530717958647692f / 256.f;
  const TW tw0 = mk_tw(lane, C);
  const TW tw1 = mk_tw(4 * (lane & 15), C);
  const TW tw2 = mk_tw(16 * (lane & 3), C);
  const int uf  = SWZ(REV4(lane));
  const int ug  = SWZ(REV4(lane + 64));
  const int ufm = SWZ(REV4((256 - lane) & 255));
  const int ugm = SWZ(REV4(192 - lane));

  const size_t rowbase = (size_t)b * 64 + h * 32;
  float4 va = reinterpret_cast<const float4*>(x + (rowbase + 2 * wave) * NPT)[lane];
  float4 vb = reinterpret_cast<const float4*>(x + (rowbase + 2 * wave + 1) * NPT)[lane];

#pragma unroll
  for (int half = 0; half < 2; ++half) {
    if (half) __syncthreads();          // write-out reads of prev half done
#pragma unroll
    for (int uu = 0; uu < 2; ++uu) {
      const int u = half * 2 + uu;
      const int p = u * 4 + wave;                  // packed-FFT index 0..15
      float4 na = va, nb = vb;
      if (u < 3) {                                 // prefetch next iteration
        const size_t nidx = rowbase + 2 * ((u + 1) * 4 + wave);
        na = reinterpret_cast<const float4*>(x + nidx * NPT)[lane];
        nb = reinterpret_cast<const float4*>(x + (nidx + 1) * NPT)[lane];
      }
      A[q3.i0] = make_float2(va.x, vb.x);
      A[q3.i1] = make_float2(va.y, vb.y);
      A[q3.i2] = make_float2(va.z, vb.z);
      A[q3.i3] = make_float2(va.w, vb.w);
      WAVE_SYNC();
      dif_stage<true >(A, q0, tw0);
      dif_stage<true >(A, q1, tw1);
      dif_stage<true >(A, q2, tw2);
      dif_stage<false>(A, q3, tw0);
      // unpack: X1(f)=0.5(Z(f)+conj(Z(-f))), X2(f)=-0.5i(Z(f)-conj(Z(-f)))
      float2 zf  = A[uf];
      float2 zg  = A[ug];
      float2 zfm = A[ufm];
      float2 zgm = A[ugm];
      const int r1 = (2 * p - half * 16) * NFP;    // staging row offsets
      const int r2 = r1 + NFP;
      Sr[r1 + lane]      = 0.5f * (zf.x + zfm.x);
      Si[r1 + lane]      = 0.5f * (zf.y - zfm.y);
      Sr[r2 + lane]      = 0.5f * (zf.y + zfm.y);
      Si[r2 + lane]      = 0.5f * (zfm.x - zf.x);
      Sr[r1 + lane + 64] = 0.5f * (zg.x + zgm.x);
      Si[r1 + lane + 64] = 0.5f * (zg.y - zgm.y);
      Sr[r2 + lane + 64] = 0.5f * (zg.y + zgm.y);
      Si[r2 + lane + 64] = 0.5f * (zgm.x - zg.x);
      if (lane == 0) {
        float2 zn = A[SWZ(REV4(128))];             // Nyquist: both spectra real
        Sr[r1 + 128] = zn.x;  Si[r1 + 128] = 0.f;
        Sr[r2 + 128] = zn.y;  Si[r2 + 128] = 0.f;
      }
      WAVE_SYNC();
      va = na; vb = nb;
    }
    __syncthreads();
    // coalesced interleaved write-out: 16 consecutive idx per f, float2 each
    const int c = threadIdx.x & 15, fg = threadIdx.x >> 4;
    const size_t baseidx = rowbase + half * 16 + c;
#pragma unroll
    for (int it = 0; it < 9; ++it) {
      int f = fg + it * 16;
      if (f < NF)
        Xc[(size_t)f * FSTRIDE + baseidx] =
            make_float2(Sr[c * NFP + f], Si[c * NFP + f]);
    }
  }
}

// ---------------------------------------------------------------------------
// k2: per-frequency complex GEMM  O[b][i] = sum_j X[b][j] * conj(W[i][j])
// Round-1 affine structure restored: padded [j][r] / [j][i] LDS tiles,
// j*68 immediate-offset b128 reads in the hot loop (NO swizzle there).
// I/O adapted to interleaved Xc plane. Accumulation written as pure-FMA
// chains (aR += x*w twice; aI += / -= ) -> 4 v_fma per accumulator pair.
// In-place over Xc (tile fully staged to LDS before writes; blocks disjoint).
// ---------------------------------------------------------------------------
__global__ __launch_bounds__(256) void k2_cgemm(float2* __restrict__ Xc,
                                                const float* __restrict__ Wtr,
                                                const float* __restrict__ Wti) {
  __shared__ __align__(16) float Xlr[64 * 68];
  __shared__ __align__(16) float Xli[64 * 68];
  __shared__ __align__(16) float Wlr[64 * 68];
  __shared__ __align__(16) float Wli[64 * 68];

  const int f  = blockIdx.y;
  const int b0 = blockIdx.x * 64;
  const int t  = threadIdx.x;
  const size_t xbase = (size_t)f * FSTRIDE + (size_t)b0 * 64;  // complex units
  const float* wpr = Wtr + (size_t)f * (KIN * KOUT);
  const float* wpi = Wti + (size_t)f * (KIN * KOUT);

  // W tile: [j][i], vector load + vector store (already in [j][i] layout)
#pragma unroll
  for (int it = 0; it < 4; ++it) {
    int n4 = (it * 256 + t) * 4;
    int j = n4 >> 6, i0 = n4 & 63;
    float4 wr = *reinterpret_cast<const float4*>(wpr + n4);
    float4 wi = *reinterpret_cast<const float4*>(wpi + n4);
    *reinterpret_cast<float4*>(&Wlr[j * 68 + i0]) = wr;
    *reinterpret_cast<float4*>(&Wli[j * 68 + i0]) = wi;
  }
  // X tile: float4 = 2 complex; transposed scalar stores -> [j][r] (pad 68)
#pragma unroll
  for (int it = 0; it < 8; ++it) {
    int n2 = (it * 256 + t) * 2;
    int j0 = n2 & 63, r = n2 >> 6;
    float4 v = *reinterpret_cast<const float4*>(
                   reinterpret_cast<const float*>(Xc + xbase) + 2 * n2);
    Xlr[(j0 + 0) * 68 + r] = v.x;  Xli[(j0 + 0) * 68 + r] = v.y;
    Xlr[(j0 + 1) * 68 + r] = v.z;  Xli[(j0 + 1) * 68 + r] = v.w;
  }
  __syncthreads();

  const int tx = t & 15, ty = t >> 4;
  const int i0 = tx * 4, r0 = ty * 4;
  float aR[4][4] = {};
  float aI[4][4] = {};

#pragma unroll 4
  for (int j = 0; j < 64; ++j) {
    float4 xr = *reinterpret_cast<const float4*>(&Xlr[j * 68 + r0]);
    float4 xi = *reinterpret_cast<const float4*>(&Xli[j * 68 + r0]);
    float4 wr = *reinterpret_cast<const float4*>(&Wlr[j * 68 + i0]);
    float4 wi = *reinterpret_cast<const float4*>(&Wli[j * 68 + i0]);
    float xra[4] = {xr.x, xr.y, xr.z, xr.w};
    float xia[4] = {xi.x, xi.y, xi.z, xi.w};
    float wra[4] = {wr.x, wr.y, wr.z, wr.w};
    float wia[4] = {wi.x, wi.y, wi.z, wi.w};
#pragma unroll
    for (int a = 0; a < 4; ++a)
#pragma unroll
      for (int c = 0; c < 4; ++c) {
        // X * conj(W), written as four independent FMA-able statements:
        aR[a][c] += xra[a] * wra[c];
        aR[a][c] += xia[a] * wia[c];
        aI[a][c] += xia[a] * wra[c];
        aI[a][c] -= xra[a] * wia[c];   // folds to v_fma with neg modifier
      }
  }

#pragma unroll
  for (int a = 0; a < 4; ++a) {
    float* gp = reinterpret_cast<float*>(Xc + xbase + (size_t)(r0 + a) * 64 + i0);
    *reinterpret_cast<float4*>(gp) =
        make_float4(aR[a][0], aI[a][0], aR[a][1], aI[a][1]);
    *reinterpret_cast<float4*>(gp + 4) =
        make_float4(aR[a][2], aI[a][2], aR[a][3], aI[a][3]);
  }
}

// ---------------------------------------------------------------------------
// k3: coalesced interleaved gather (prefetched), conjugate-symmetric spectrum
// written at digit-reversed slots, in-place DIT radix-4 inverse FFT (natural-
// order output), packed: one complex iFFT -> two real output blocks.
// ---------------------------------------------------------------------------
__global__ __launch_bounds__(256) void k3_irfft(const float2* __restrict__ Oc,
                                                float* __restrict__ out) {
  __shared__ float2 fbuf[4][256];
  __shared__ float Sr[16 * NFP];
  __shared__ float Si[16 * NFP];
  const int wave = threadIdx.x >> 6, lane = threadIdx.x & 63;
  const int b = blockIdx.x >> 1, h = blockIdx.x & 1;
  float2* A = fbuf[wave];
  const int c = threadIdx.x & 15, fg = threadIdx.x >> 4;
  const size_t rowbase = (size_t)b * 64 + h * 32;

  const Quad q0 = mkquad(lane, 64);
  const Quad q1 = mkquad(((lane >> 4) << 6) + (lane & 15), 16);
  const Quad q2 = mkquad(((lane >> 2) << 4) + (lane & 3), 4);
  const Quad q3 = mkquad(lane << 2, 1);
  const float C = 6.28318530717958647692f / 256.f;
  const TW tw0 = mk_tw(lane, C);
  const TW tw1 = mk_tw(4 * (lane & 15), C);
  const TW tw2 = mk_tw(16 * (lane & 3), C);
  const int wf  = SWZ(REV4(lane));
  const int wg  = SWZ(REV4(lane + 64));
  const int wfm = SWZ(REV4((256 - lane) & 255));  // lane>=1 only
  const int wgm = SWZ(REV4(192 - lane));

  // prefetch half-0 gathers
  float2 gv[9], nv[9];
#pragma unroll
  for (int it = 0; it < 9; ++it) {
    int f = fg + it * 16;
    gv[it] = (f < NF) ? Oc[(size_t)f * FSTRIDE + rowbase + c]
                      : make_float2(0.f, 0.f);
  }
#pragma unroll
  for (int half = 0; half < 2; ++half) {
    if (half == 0) {
      // issue half-1 gathers now; latency hides under half-0 FFT phase
#pragma unroll
      for (int it = 0; it < 9; ++it) {
        int f = fg + it * 16;
        nv[it] = (f < NF) ? Oc[(size_t)f * FSTRIDE + rowbase + 16 + c]
                          : make_float2(0.f, 0.f);
      }
    }
    if (half) __syncthreads();          // FFT reads of prev half done
#pragma unroll
    for (int it = 0; it < 9; ++it) {
      int f = fg + it * 16;
      if (f < NF) { Sr[c * NFP + f] = gv[it].x; Si[c * NFP + f] = gv[it].y; }
    }
    __syncthreads();
#pragma unroll
    for (int uu = 0; uu < 2; ++uu) {
      const int u = half * 2 + uu;
      const int p = u * 4 + wave;
      const int r1 = (2 * p - half * 16) * NFP, r2 = r1 + NFP;
      float a1r = Sr[r1 + lane],      a1i = Si[r1 + lane];
      float b1r = Sr[r1 + lane + 64], b1i = Si[r1 + lane + 64];
      float a2r = Sr[r2 + lane],      a2i = Si[r2 + lane];
      float b2r = Sr[r2 + lane + 64], b2i = Si[r2 + lane + 64];
      // Z(f) = O1(f) + i*O2(f);  Z(256-f) = conj(O1(f)) + i*conj(O2(f))
      A[wf]  = make_float2(a1r - a2i, a1i + a2r);            // f = 0..63
      A[wg]  = make_float2(b1r - b2i, b1i + b2r);            // f = 64..127
      if (lane) A[wfm] = make_float2(a1r + a2i, a2r - a1i);  // f = 193..255
      A[wgm] = make_float2(b1r + b2i, b2r - b1i);            // f = 129..192
      if (lane == 0) {
        float n1r = Sr[r1 + 128], n1i = Si[r1 + 128];
        float n2r = Sr[r2 + 128], n2i = Si[r2 + 128];
        A[SWZ(REV4(128))] = make_float2(n1r - n2i, n1i + n2r);
      }
      WAVE_SYNC();
      dit_stage<false>(A, q3, tw0);
      dit_stage<true >(A, q2, tw2);
      dit_stage<true >(A, q1, tw1);
      dit_stage<true >(A, q0, tw0);
      const float s = 1.0f / 256.f;
      float2 e0 = A[q3.i0], e1 = A[q3.i1], e2 = A[q3.i2], e3 = A[q3.i3];
      float4 o1 = make_float4(e0.x * s, e1.x * s, e2.x * s, e3.x * s);
      float4 o2 = make_float4(e0.y * s, e1.y * s, e2.y * s, e3.y * s);
      const size_t idx1 = rowbase + 2 * p;
      reinterpret_cast<float4*>(out + idx1 * NPT)[lane] = o1;
      reinterpret_cast<float4*>(out + (idx1 + 1) * NPT)[lane] = o2;
      WAVE_SYNC();                      // output reads done before next build
    }
#pragma unroll
    for (int it = 0; it < 9; ++it) gv[it] = nv[it];
  }
}

// ---------------------------------------------------------------------------
extern "C" void kernel_launch(void* const* d_in, const int* in_sizes, int n_in,
                              void* d_out, int out_size, void* d_ws, size_t ws_size,
                              hipStream_t stream) {
  const float* x   = (const float*)d_in[0];
  const float* Wre = (const float*)d_in[1];
  const float* Wim = (const float*)d_in[2];
  float* out = (float*)d_out;
  float* ws  = (float*)d_ws;

  float2* Xc = reinterpret_cast<float2*>(ws);  // interleaved plane [f][b*64+j]
  float* Wtr = ws + 2 * XPLANE;                // [f][j*64+i]
  float* Wti = Wtr + WPLANE;
  // ws use: (2*XPLANE + 2*WPLANE)*4 B ~= 139.5 MB

  hipLaunchKernelGGL(k0_wtrans, dim3(128, 5), dim3(256), 0, stream,
                     Wre, Wim, Wtr, Wti);
  hipLaunchKernelGGL(k1_rfft, dim3(BATCH * 2), dim3(256), 0, stream,
                     x, Xc);
  hipLaunchKernelGGL(k2_cgemm, dim3(BATCH / 64, NF), dim3(256), 0, stream,
                     Xc, Wtr, Wti);
  hipLaunchKernelGGL(k3_irfft, dim3(BATCH * 2), dim3(256), 0, stream,
                     Xc, out);
}